// Round 3
// baseline (210.007 us; speedup 1.0000x reference)
//
#include <hip/hip_runtime.h>

// Problem constants (from reference setup_inputs): B=2, C=16, D=64, H=128, W=128
#define BB 2
#define CC 16
#define SEGS (BB * CC)          // 32 (b,c) segments
#define NVOX (64 * 128 * 128)   // voxels per batch = 1048576 = 2^20
#define N4   (NVOX / 4)         // float4-granular voxels per batch = 262144 = 2^18
#define N8   (NVOX / 8)         // 8-voxel tiles per batch = 131072 = 2^17
#define NBLK 1024               // main-pass blocks (B * NVOX / 8 / 256)

typedef float v4f __attribute__((ext_vector_type(4)));

// Main pass: one thread = 8 consecutive voxels (2 float4 per class -> 32 NT loads,
// 16 address pairs with +16B immediate). Register log-sum-exp, LDS-atomic class
// accumulation, NON-ATOMIC per-block partial stores (every slot written -> no init
// kernel needed despite 0xAA workspace poison). vs round 2: halves per-byte
// overhead (waves 8192->4096, blocks 2048->1024, y/address/LDS/partial work /2).
__global__ __launch_bounds__(256) void cwce_main(const float* __restrict__ x,
                                                 const int* __restrict__ y,
                                                 float* __restrict__ part_sum,
                                                 unsigned* __restrict__ part_cnt) {
    __shared__ float    s_sum[CC];
    __shared__ unsigned s_cnt[CC];
    const int t = threadIdx.x;
    if (t < CC) { s_sum[t] = 0.0f; s_cnt[t] = 0u; }
    __syncthreads();

    const unsigned gid = blockIdx.x * 256u + t;      // [0, 262144)
    const unsigned b   = gid >> 17;                  // 131072 threads per batch
    const unsigned n8  = gid & (N8 - 1);

    // float4-granule base: voxel tile starts at float4 index n8*2 within each class row
    const v4f* xb = (const v4f*)x + (size_t)(b * CC) * N4 + (size_t)n8 * 2;
    const int4 lab4a = ((const int4*)y)[(size_t)gid * 2 + 0];
    const int4 lab4b = ((const int4*)y)[(size_t)gid * 2 + 1];

    // Load the full 16-class x 8-voxel tile into registers (one HBM pass).
    // Nontemporal: x is strictly single-use streaming data.
    float xv[CC][8];
#pragma unroll
    for (int c = 0; c < CC; ++c) {
        const v4f* p = xb + (size_t)c * N4;
        v4f va = __builtin_nontemporal_load(p);       // voxels 0..3
        v4f vb = __builtin_nontemporal_load(p + 1);   // voxels 4..7 (+16B imm offset)
        xv[c][0] = va.x; xv[c][1] = va.y; xv[c][2] = va.z; xv[c][3] = va.w;
        xv[c][4] = vb.x; xv[c][5] = vb.y; xv[c][6] = vb.z; xv[c][7] = vb.w;
    }
    const int labs[8] = {lab4a.x, lab4a.y, lab4a.z, lab4a.w,
                         lab4b.x, lab4b.y, lab4b.z, lab4b.w};

#pragma unroll
    for (int j = 0; j < 8; ++j) {
        float m = xv[0][j];
#pragma unroll
        for (int c = 1; c < CC; ++c) m = fmaxf(m, xv[c][j]);
        const int lj = labs[j];
        float s = 0.0f, xy = 0.0f;
#pragma unroll
        for (int c = 0; c < CC; ++c) {
            s += __expf(xv[c][j] - m);
            if (c == lj) xy = xv[c][j];   // cndmask select of x[label]
        }
        const float nll = m + __logf(s) - xy;
        atomicAdd(&s_sum[lj], nll);
        atomicAdd(&s_cnt[lj], 1u);
    }
    __syncthreads();

    // Per-block partials, no atomics: slot [blockIdx][c]. All 1024*16 slots are
    // written every launch, so the 0xAA re-poison never needs a zeroing pass.
    if (t < CC) {
        part_sum[blockIdx.x * CC + t] = s_sum[t];
        part_cnt[blockIdx.x * CC + t] = s_cnt[t];
    }
}

// Final: reduce 1024x16 partials -> per-(b,c) mean (empty class -> 0), then
// sum/(B*C). One block of 256 threads; reads 128 KB of partials.
__global__ void cwce_final(const float* __restrict__ part_sum,
                           const unsigned* __restrict__ part_cnt,
                           float* __restrict__ out) {
    __shared__ float fs[16][CC];
    __shared__ float fc[16][CC];
    const int t = threadIdx.x;     // 256 threads
    const int c = t & 15;          // class
    const int g = t >> 4;          // 16 groups; group g owns block-rows [g*64,(g+1)*64)
    float s = 0.0f, n = 0.0f;
    for (int r = g * 64; r < (g + 1) * 64; ++r) {
        s += part_sum[r * CC + c];
        n += (float)part_cnt[r * CC + c];   // counts < 2^24: exact in float
    }
    fs[g][c] = s;
    fc[g][c] = n;
    __syncthreads();

    // Block-rows [0,512) are batch 0, [512,1024) batch 1 -> groups g<8 are b=0,
    // g>=8 are b=1. Thread t<32 finishes segment (b=t>>4, c=t&15).
    if (t < 64) {                  // whole first wave participates in the shfl tree
        float v = 0.0f;
        if (t < SEGS) {
            const int b = t >> 4;
            float ts = 0.0f, tn = 0.0f;
#pragma unroll
            for (int k = 0; k < 8; ++k) { ts += fs[b * 8 + k][c]; tn += fc[b * 8 + k][c]; }
            v = (tn > 0.0f) ? (ts / tn) : 0.0f;   // absent class contributes 0
        }
#pragma unroll
        for (int off = 32; off >= 1; off >>= 1) v += __shfl_down(v, off);
        if (t == 0) out[0] = v * (1.0f / SEGS);
    }
}

extern "C" void kernel_launch(void* const* d_in, const int* in_sizes, int n_in,
                              void* d_out, int out_size, void* d_ws, size_t ws_size,
                              hipStream_t stream) {
    const float* x = (const float*)d_in[0];
    const int*   y = (const int*)d_in[1];
    float*       out = (float*)d_out;

    float*    part_sum = (float*)d_ws;                         // 1024*16 floats (64 KB)
    unsigned* part_cnt = (unsigned*)(part_sum + NBLK * CC);    // 1024*16 uints  (64 KB)

    // total threads = B * NVOX / 8 = 262144 -> 1024 blocks of 256. No init kernel.
    cwce_main<<<NBLK, 256, 0, stream>>>(x, y, part_sum, part_cnt);
    cwce_final<<<1, 256, 0, stream>>>(part_sum, part_cnt, out);
}

// Round 4
// 194.167 us; speedup vs baseline: 1.0816x; 1.0816x over previous
//
#include <hip/hip_runtime.h>

// Problem constants (from reference setup_inputs): B=2, C=16, D=64, H=128, W=128
#define BB 2
#define CC 16
#define CH 8                    // class chunk for online-LSE (2 chunks of 8)
#define SEGS (BB * CC)          // 32 (b,c) segments
#define NVOX (64 * 128 * 128)   // voxels per batch = 1048576 = 2^20
#define N4   (NVOX / 4)         // float4-granular voxels per batch = 262144 = 2^18
#define NBLK 2048               // main-pass blocks (B * NVOX / 4 / 256)

typedef float v4f __attribute__((ext_vector_type(4)));

// Main pass: one thread = 4 consecutive voxels (round-2 geometry, the best so far).
// ONLINE log-sum-exp over two chunks of 8 classes: chunk regs are reused, cutting
// live VGPRs from ~64+ to ~32+ so the kernel fits 6 waves/SIMD (launch_bounds cap)
// instead of ~4. One extra exp per voxel for the chunk merge (rescale), numerically
// safe: within-chunk exponents are <= 0, rescale factor exp(m0-m) <= 1.
// NT float4 loads (x is single-use), LDS-atomic class histogram, non-atomic
// per-block partial stores (every slot written -> no init kernel despite 0xAA poison).
__global__ __launch_bounds__(256, 6) void cwce_main(const float* __restrict__ x,
                                                    const int* __restrict__ y,
                                                    float* __restrict__ part_sum,
                                                    unsigned* __restrict__ part_cnt) {
    __shared__ float    s_sum[CC];
    __shared__ unsigned s_cnt[CC];
    const int t = threadIdx.x;
    if (t < CC) { s_sum[t] = 0.0f; s_cnt[t] = 0u; }
    __syncthreads();

    const unsigned gid = blockIdx.x * 256u + t;      // [0, 524288)
    const unsigned b   = gid >> 18;                  // 262144 threads per batch
    const unsigned n4  = gid & (N4 - 1);

    const v4f* xb = (const v4f*)x + (size_t)(b * CC) * N4 + n4;
    const int4 lab4 = ((const int4*)y)[gid];
    const int labs[4] = {lab4.x, lab4.y, lab4.z, lab4.w};

    float xv[CH][4];              // one chunk of 8 classes x 4 voxels (reused)
    float m[4], s[4], xy[4];      // running LSE state per voxel

    // ---- chunk 0: classes 0..7 ----
#pragma unroll
    for (int c = 0; c < CH; ++c) {
        v4f v = __builtin_nontemporal_load(xb + (size_t)c * N4);
        xv[c][0] = v.x; xv[c][1] = v.y; xv[c][2] = v.z; xv[c][3] = v.w;
    }
#pragma unroll
    for (int j = 0; j < 4; ++j) {
        float mm = xv[0][j];
#pragma unroll
        for (int c = 1; c < CH; ++c) mm = fmaxf(mm, xv[c][j]);
        float ss = 0.0f, sel = 0.0f;
#pragma unroll
        for (int c = 0; c < CH; ++c) {
            ss += __expf(xv[c][j] - mm);
            if (c == labs[j]) sel = xv[c][j];   // cndmask select of x[label]
        }
        m[j] = mm; s[j] = ss; xy[j] = sel;
    }

    // ---- chunk 1: classes 8..15 (reuses xv registers) ----
#pragma unroll
    for (int c = 0; c < CH; ++c) {
        v4f v = __builtin_nontemporal_load(xb + (size_t)(c + CH) * N4);
        xv[c][0] = v.x; xv[c][1] = v.y; xv[c][2] = v.z; xv[c][3] = v.w;
    }
#pragma unroll
    for (int j = 0; j < 4; ++j) {
        float m1 = xv[0][j];
#pragma unroll
        for (int c = 1; c < CH; ++c) m1 = fmaxf(m1, xv[c][j]);
        const float mn = fmaxf(m[j], m1);
        float ss = 0.0f, sel = xy[j];
#pragma unroll
        for (int c = 0; c < CH; ++c) {
            ss += __expf(xv[c][j] - mn);
            if (c + CH == labs[j]) sel = xv[c][j];
        }
        const float sfull = s[j] * __expf(m[j] - mn) + ss;   // online merge
        const float nll = mn + __logf(sfull) - sel;
        const int lj = labs[j];
        atomicAdd(&s_sum[lj], nll);
        atomicAdd(&s_cnt[lj], 1u);
    }
    __syncthreads();

    // Per-block partials, no atomics: slot [blockIdx][c]. All 2048*16 slots are
    // written every launch, so the 0xAA re-poison never needs a zeroing pass.
    if (t < CC) {
        part_sum[blockIdx.x * CC + t] = s_sum[t];
        part_cnt[blockIdx.x * CC + t] = s_cnt[t];
    }
}

// Final: reduce 2048x16 partials -> per-(b,c) mean (empty class -> 0), then
// sum/(B*C). One block of 256 threads; reads 256 KB of partials.
__global__ void cwce_final(const float* __restrict__ part_sum,
                           const unsigned* __restrict__ part_cnt,
                           float* __restrict__ out) {
    __shared__ float fs[16][CC];
    __shared__ float fc[16][CC];
    const int t = threadIdx.x;     // 256 threads
    const int c = t & 15;          // class
    const int g = t >> 4;          // 16 groups; group g owns block-rows [g*128,(g+1)*128)
    float s = 0.0f, n = 0.0f;
    for (int r = g * 128; r < (g + 1) * 128; ++r) {
        s += part_sum[r * CC + c];
        n += (float)part_cnt[r * CC + c];   // counts < 2^24: exact in float
    }
    fs[g][c] = s;
    fc[g][c] = n;
    __syncthreads();

    // Block-rows [0,1024) are batch 0, [1024,2048) batch 1 -> groups g<8 are b=0,
    // g>=8 are b=1. Thread t<32 finishes segment (b=t>>4, c=t&15).
    if (t < 64) {                  // whole first wave participates in the shfl tree
        float v = 0.0f;
        if (t < SEGS) {
            const int b = t >> 4;
            float ts = 0.0f, tn = 0.0f;
#pragma unroll
            for (int k = 0; k < 8; ++k) { ts += fs[b * 8 + k][c]; tn += fc[b * 8 + k][c]; }
            v = (tn > 0.0f) ? (ts / tn) : 0.0f;   // absent class contributes 0
        }
#pragma unroll
        for (int off = 32; off >= 1; off >>= 1) v += __shfl_down(v, off);
        if (t == 0) out[0] = v * (1.0f / SEGS);
    }
}

extern "C" void kernel_launch(void* const* d_in, const int* in_sizes, int n_in,
                              void* d_out, int out_size, void* d_ws, size_t ws_size,
                              hipStream_t stream) {
    const float* x = (const float*)d_in[0];
    const int*   y = (const int*)d_in[1];
    float*       out = (float*)d_out;

    float*    part_sum = (float*)d_ws;                         // 2048*16 floats (128 KB)
    unsigned* part_cnt = (unsigned*)(part_sum + NBLK * CC);    // 2048*16 uints  (128 KB)

    // total threads = B * NVOX / 4 = 524288 -> 2048 blocks of 256. No init kernel.
    cwce_main<<<NBLK, 256, 0, stream>>>(x, y, part_sum, part_cnt);
    cwce_final<<<1, 256, 0, stream>>>(part_sum, part_cnt, out);
}